// Round 27
// baseline (171.611 us; speedup 1.0000x reference)
//
#include <hip/hip_runtime.h>
#include <math.h>

// x [2,64,16,64,64], y [2,128,8,32,32]
// w_down_h [64,128], w_down_l [64,64], w_flow [3,128,3,3,3],
// w_att_atten [64,64], w_att_conv [64,64]
// out = grid_sample(y, vgrid) -> [2,128,16,64,64] fp32

// ws layout (float offsets)
#define MEANX_OFF  0
#define WEFF_OFF   128        // weff[n][i][o][tap] = [2][64][3][27] = 10368 floats
#define HF_OFF     16384
#define HFUP_OFF   1064960    // 8388608 floats
#define VG_OFF     9453568    // 393216 floats
#define ZPAGE_OFF  9846784    // 64 floats, zeroed each launch
#define YT_OFF     9846848    // 2097152 floats

// ---------------- kernel A: kmean (0..127) + kconvh (128..383) + ktrans (384..895) ----------------
__global__ __launch_bounds__(256) void kearly(const float* __restrict__ x,
                                              const float* __restrict__ y,
                                              const float* __restrict__ wdh,
                                              float* __restrict__ meanx,
                                              float* __restrict__ hf,
                                              float* __restrict__ yt,
                                              float* __restrict__ zpage) {
    const int blk = blockIdx.x;
    if (blk < 128) {
        // ---- kmean ----
        if (blk == 0 && threadIdx.x < 64) zpage[threadIdx.x] = 0.f;
        int ch = blk;  // 0..127  (n*64+c)
        const float4* base = (const float4*)(x + (size_t)ch * 65536);
        float s = 0.f;
        for (int j = threadIdx.x; j < 16384; j += 256) {
            float4 v = base[j];
            s += v.x + v.y + v.z + v.w;
        }
        __shared__ float red[256];
        red[threadIdx.x] = s;
        __syncthreads();
        for (int off = 128; off > 0; off >>= 1) {
            if (threadIdx.x < off) red[threadIdx.x] += red[threadIdx.x + off];
            __syncthreads();
        }
        if (threadIdx.x == 0) meanx[ch] = red[0] * (1.0f / 65536.0f);
    } else if (blk < 384) {
        // ---- kconvh ----
        const int b = blk - 128;    // 0..255
        const int n = b >> 7;
        const int r = b & 127;
        const int os = r & 3;       // 16 outputs each
        const int tile = r >> 2;    // 0..31, 256 points
        const int p = tile * 256 + threadIdx.x;
        const float* yb = y + (size_t)n * 128 * 8192 + p;

        float acc[16];
#pragma unroll
        for (int o = 0; o < 16; ++o) acc[o] = 0.f;

        for (int i = 0; i < 128; i += 4) {
            const float yi0 = yb[(size_t)(i + 0) * 8192];
            const float yi1 = yb[(size_t)(i + 1) * 8192];
            const float yi2 = yb[(size_t)(i + 2) * 8192];
            const float yi3 = yb[(size_t)(i + 3) * 8192];
#pragma unroll
            for (int o = 0; o < 16; ++o) {
                float a = acc[o];
                a = fmaf(wdh[(os * 16 + o) * 128 + i + 0], yi0, a);
                a = fmaf(wdh[(os * 16 + o) * 128 + i + 1], yi1, a);
                a = fmaf(wdh[(os * 16 + o) * 128 + i + 2], yi2, a);
                a = fmaf(wdh[(os * 16 + o) * 128 + i + 3], yi3, a);
                acc[o] = a;
            }
        }
        float* ob = hf + (size_t)(n * 64 + os * 16) * 8192 + p;
#pragma unroll
        for (int o = 0; o < 16; ++o)
            ob[(size_t)o * 8192] = acc[o];
    } else {
        // ---- ktrans: y -> channel-last yt [n][8192][128] ----
        int b = blk - 384;        // 0..511
        int n = b >> 8;
        int rem = b & 255;        // 2 c-tiles * 128 s-tiles
        int ct = rem >> 7, st = rem & 127;
        int c0 = ct * 64, s0 = st * 64;
        __shared__ float t[64][65];
        int tx = threadIdx.x & 63, ty = threadIdx.x >> 6;  // 4 rows/pass
#pragma unroll
        for (int k = 0; k < 16; ++k)
            t[ty + 4 * k][tx] = y[((size_t)(n * 128 + c0 + ty + 4 * k)) * 8192 + s0 + tx];
        __syncthreads();
#pragma unroll
        for (int k = 0; k < 16; ++k)
            yt[((size_t)(n * 8192 + s0 + ty + 4 * k)) * 128 + c0 + tx] = t[tx][ty + 4 * k];
    }
}

// ---------------- kernel B: SE weights + fold low-branch conv weights -> weff ----------------
__global__ __launch_bounds__(256) void kprep(const float* __restrict__ wdl,
                                             const float* __restrict__ watt,
                                             const float* __restrict__ wconv,
                                             const float* __restrict__ wflow,
                                             const float* __restrict__ meanx,
                                             float* __restrict__ weff) {
    const int n = blockIdx.x;   // 2
    const int tid = threadIdx.x;
    __shared__ float s_wdl[4096];   // wdl[j][i]; later reused as s_comb[i][c]
    __shared__ float s_wcT[4096];   // wconv transposed: [j][o]
    __shared__ float s_flow[5184];  // wflow low half: [o*1728 + c*27 + tap]
    __shared__ float pooled[64], sc[64];
    for (int k = tid; k < 4096; k += 256) {
        s_wdl[k] = wdl[k];
        int o = k >> 6, j = k & 63;
        s_wcT[j * 64 + o] = wconv[k];
    }
    for (int k = tid; k < 5184; k += 256) {
        int o = k / 1728, r = k - o * 1728;
        s_flow[k] = wflow[o * 3456 + 1728 + r];
    }
    __syncthreads();
    if (tid < 64) {
        float p = 0.f;
        for (int i = 0; i < 64; ++i) p += s_wdl[tid * 64 + i] * meanx[n * 64 + i];
        pooled[tid] = p;
    }
    __syncthreads();
    if (tid < 64) {
        float a = 0.f;
        for (int i = 0; i < 64; ++i) a += watt[tid * 64 + i] * pooled[i];
        sc[tid] = 1.f + 1.f / (1.f + expf(-a));
    }
    __syncthreads();
    float wc[16];
#pragma unroll
    for (int k = 0; k < 16; ++k) {
        const int idx = tid + 256 * k;
        const int o = idx & 63, i = idx >> 6;
        float acc = 0.f;
#pragma unroll 8
        for (int j = 0; j < 64; ++j)
            acc += s_wcT[j * 64 + o] * (sc[j] * s_wdl[j * 64 + i]);
        wc[k] = acc;
    }
    __syncthreads();
#pragma unroll
    for (int k = 0; k < 16; ++k) {
        const int idx = tid + 256 * k;
        const int o = idx & 63, i = idx >> 6;
        s_wdl[i * 64 + o] = wc[k];   // s_comb[i*64 + c] = W_comb[c][i]
    }
    __syncthreads();
    for (int e = tid; e < 5184; e += 256) {
        const int i = e / 81, r = e - i * 81;
        const int o = r / 27, tap = r - o * 27;
        float acc = 0.f;
#pragma unroll 8
        for (int c = 0; c < 64; ++c)
            acc += s_flow[o * 1728 + c * 27 + tap] * s_wdl[i * 64 + c];
        weff[n * 5184 + e] = acc;
    }
}

// ---------------- kernel C: fused kflowp_low (blocks 0..1023) + kups (1024..17407) ----------------
__global__ __launch_bounds__(256) void kmid(const float* __restrict__ x,
                                            const float* __restrict__ ws,
                                            const float* __restrict__ weff,
                                            const float* __restrict__ hf,
                                            float* __restrict__ hfup,
                                            float* __restrict__ part) {
    const int blk = blockIdx.x;
    if (blk < 1024) {
        // ---- kflowp_low: splits 8..15, source x, weights weff ----
        const int tid = threadIdx.x;
        const int sp = blk & 7;              // 0..7 -> x channels sp*8..sp*8+7
        const int tile = blk >> 3;           // 0..127
        const int n = tile >> 6;
        const int t = tile & 63;
        const int td = t >> 4, th = (t >> 2) & 3, tw = t & 3;
        const int d0 = td * 4, h0 = th * 16, w0 = tw * 16;
        const int xo = tid & 3, ty = (tid >> 2) & 15, tz = tid >> 6;
        const int wv = tid >> 6;

        __shared__ float lds[3][2048];

        const float* gb = x + (size_t)(n * 64 + sp * 8) * 65536;
        const float* zp = ws + ZPAGE_OFF;

        const float* addrk[8];
        int vmask = 0;
#pragma unroll
        for (int k = 0; k < 8; ++k) {
            const int e = tid + 256 * k;
            const int r = e / 18;
            const int lx = e - r * 18;
            const int z = r / 18;
            const int ly = r - z * 18;
            const int gz = d0 - 1 + z, gy = h0 - 1 + ly, gx = w0 - 1 + lx;
            const bool ok = (e < 1944) && ((unsigned)gz < 16u) && ((unsigned)gy < 64u) &&
                            ((unsigned)gx < 64u);
            addrk[k] = ok ? (gb + (gz * 4096 + gy * 64 + gx)) : zp;
            vmask |= (ok ? 1 : 0) << k;
        }

#define STAGEL(BUFI)                                                                  \
    {                                                                                 \
        _Pragma("unroll")                                                             \
        for (int k = 0; k < 8; ++k) {                                                 \
            __builtin_amdgcn_global_load_lds(                                         \
                (const __attribute__((address_space(1))) unsigned int*)(addrk[k]),    \
                (__attribute__((address_space(3))) unsigned int*)                     \
                    (&lds[BUFI][wv * 64 + 256 * k]),                                  \
                4, 0, 0);                                                             \
            addrk[k] += ((vmask >> k) & 1) ? 65536 : 0;                               \
        }                                                                             \
    }

        float acc[3][4];
#pragma unroll
        for (int o = 0; o < 3; ++o)
#pragma unroll
            for (int j = 0; j < 4; ++j) acc[o][j] = 0.f;

        STAGEL(0);

        for (int ci = 0; ci < 8; ++ci) {
            const int cur = ci % 3;
            if (ci < 7) {
                STAGEL((ci + 1) % 3);
                asm volatile("s_waitcnt vmcnt(8)" ::: "memory");
            } else {
                asm volatile("s_waitcnt vmcnt(0)" ::: "memory");
            }
            __builtin_amdgcn_s_barrier();
            __builtin_amdgcn_sched_barrier(0);

            const int cidx = __builtin_amdgcn_readfirstlane(sp * 8 + ci);
            const float* wbase = weff + (size_t)n * 5184 + (size_t)cidx * 81;
            const float* buf = lds[cur];
#pragma unroll
            for (int dz = 0; dz < 3; ++dz) {
#pragma unroll
                for (int dy = 0; dy < 3; ++dy) {
                    const float* rp = &buf[((tz + dz) * 18 + ty + dy) * 18 + 4 * xo];
                    const float2 a0 = *(const float2*)(rp);
                    const float2 a1 = *(const float2*)(rp + 2);
                    const float2 a2 = *(const float2*)(rp + 4);
                    const float v[6] = {a0.x, a0.y, a1.x, a1.y, a2.x, a2.y};
                    float wq[3][3];
#pragma unroll
                    for (int o = 0; o < 3; ++o)
#pragma unroll
                        for (int dx = 0; dx < 3; ++dx)
                            wq[o][dx] = wbase[o * 27 + (dz * 3 + dy) * 3 + dx];
#pragma unroll
                    for (int o = 0; o < 3; ++o)
#pragma unroll
                        for (int j = 0; j < 4; ++j)
#pragma unroll
                            for (int dx = 0; dx < 3; ++dx)
                                acc[o][j] = fmaf(wq[o][dx], v[j + dx], acc[o][j]);
                }
            }
        }
#undef STAGEL

        const int oz = d0 + tz, oy = h0 + ty, ox = w0 + 4 * xo;
        const size_t base = ((size_t)((sp + 8) * 2 + n)) * 3 * 65536;
        const int p = oz * 4096 + oy * 64 + ox;
#pragma unroll
        for (int o = 0; o < 3; ++o)
            *(float4*)(part + base + (size_t)o * 65536 + p) =
                make_float4(acc[o][0], acc[o][1], acc[o][2], acc[o][3]);
    } else {
        // ---- kups (2 w-outputs/thread) ----
        int id2 = (blk - 1024) * 256 + threadIdx.x;  // 4194304 total
        int wp = id2 & 31, h = (id2 >> 5) & 63, d = (id2 >> 11) & 15;
        int c = (id2 >> 15) & 63, n = id2 >> 21;
        const float SD = 7.0f / 15.0f, SH = 31.0f / 63.0f;
        float pd = (float)d * SD, ph = (float)h * SH;
        int z0 = (int)pd; if (z0 > 7) z0 = 7;
        int z1 = min(z0 + 1, 7); float fz = pd - (float)z0;
        int y0 = (int)ph; if (y0 > 31) y0 = 31;
        int y1 = min(y0 + 1, 31); float fy = ph - (float)y0;

        const int w0i = 2 * wp, w1i = 2 * wp + 1;
        float pw0 = (float)w0i * SH, pw1 = (float)w1i * SH;
        int xa = (int)pw0; if (xa > 31) xa = 31;
        float fx0 = pw0 - (float)xa;
        int xb2 = (int)pw1; if (xb2 > 31) xb2 = 31;
        float fx1 = pw1 - (float)xb2;

        const float* b = hf + (size_t)(n * 64 + c) * 8192;
        const int r00 = (z0 * 32 + y0) * 32, r01 = (z0 * 32 + y1) * 32;
        const int r10 = (z1 * 32 + y0) * 32, r11 = (z1 * 32 + y1) * 32;
        const float wzy00 = (1.f - fz) * (1.f - fy), wzy01 = (1.f - fz) * fy;
        const float wzy10 = fz * (1.f - fy), wzy11 = fz * fy;

        float colv[3];
#pragma unroll
        for (int j = 0; j < 3; ++j) {
            int xc = min(xa + j, 31);
            colv[j] = wzy00 * b[r00 + xc] + wzy01 * b[r01 + xc] +
                      wzy10 * b[r10 + xc] + wzy11 * b[r11 + xc];
        }
        float o0 = colv[0] + (colv[1] - colv[0]) * fx0;
        int i1 = xb2 - xa;  // 0 or 1
        float lo = (i1 == 0) ? colv[0] : colv[1];
        float hi = (i1 == 0) ? colv[1] : colv[2];
        float o1 = lo + (hi - lo) * fx1;

        *(float2*)(hfup + ((size_t)id2 * 2)) = make_float2(o0, o1);
    }
}

// ---------------- kernel F: kflowp_high — splits 0..7 (hfup, wflow), int-offset form ----------------
__global__ __launch_bounds__(256) void kflowp(const float* __restrict__ ws,
                                              const float* __restrict__ wflow,
                                              float* __restrict__ part) {
    const int tid = threadIdx.x;
    const int b = blockIdx.x;            // 1024
    const int split = b & 7;             // 8 channels each (hfup channels)
    const int tile = b >> 3;             // 0..127
    const int n = tile >> 6;
    const int t = tile & 63;
    const int td = t >> 4, th = (t >> 2) & 3, tw = t & 3;
    const int d0 = td * 4, h0 = th * 16, w0 = tw * 16;
    const int xo = tid & 3, ty = (tid >> 2) & 15, tz = tid >> 6;
    const int wv = tid >> 6;

    __shared__ float lds[3][2048];

    const int srcb = HFUP_OFF + (n * 64 + split * 8) * 65536;

    int woff[8];
#pragma unroll
    for (int k = 0; k < 8; ++k) {
        const int e = tid + 256 * k;
        const int r = e / 18;
        const int lx = e - r * 18;
        const int z = r / 18;
        const int ly = r - z * 18;
        const int gz = d0 - 1 + z, gy = h0 - 1 + ly, gx = w0 - 1 + lx;
        const bool ok = (e < 1944) && ((unsigned)gz < 16u) && ((unsigned)gy < 64u) &&
                        ((unsigned)gx < 64u);
        woff[k] = ok ? (srcb + gz * 4096 + gy * 64 + gx) : ZPAGE_OFF;
    }

#define STAGE(BUFI, CI)                                                               \
    {                                                                                 \
        _Pragma("unroll")                                                             \
        for (int k = 0; k < 8; ++k) {                                                 \
            const int off = woff[k] + ((woff[k] < ZPAGE_OFF) ? (CI) * 65536 : 0);     \
            __builtin_amdgcn_global_load_lds(                                         \
                (const __attribute__((address_space(1))) unsigned int*)(ws + off),    \
                (__attribute__((address_space(3))) unsigned int*)                     \
                    (&lds[BUFI][wv * 64 + 256 * k]),                                  \
                4, 0, 0);                                                             \
        }                                                                             \
    }

    float acc[3][4];
#pragma unroll
    for (int o = 0; o < 3; ++o)
#pragma unroll
        for (int j = 0; j < 4; ++j) acc[o][j] = 0.f;

    STAGE(0, 0);

    for (int ci = 0; ci < 8; ++ci) {
        const int cur = ci % 3;
        if (ci < 7) {
            STAGE((ci + 1) % 3, ci + 1);
            asm volatile("s_waitcnt vmcnt(8)" ::: "memory");
        } else {
            asm volatile("s_waitcnt vmcnt(0)" ::: "memory");
        }
        __builtin_amdgcn_s_barrier();
        __builtin_amdgcn_sched_barrier(0);

        const int cgs = __builtin_amdgcn_readfirstlane(split * 8 + ci);
        const float* wb = wflow + (size_t)cgs * 27;   // SGPR base -> s_loads
        const float* buf = lds[cur];
#pragma unroll
        for (int dz = 0; dz < 3; ++dz) {
#pragma unroll
            for (int dy = 0; dy < 3; ++dy) {
                const float* rp = &buf[((tz + dz) * 18 + ty + dy) * 18 + 4 * xo];
                const float2 a0 = *(const float2*)(rp);
                const float2 a1 = *(const float2*)(rp + 2);
                const float2 a2 = *(const float2*)(rp + 4);
                const float v[6] = {a0.x, a0.y, a1.x, a1.y, a2.x, a2.y};
                float wq[3][3];
#pragma unroll
                for (int o = 0; o < 3; ++o)
#pragma unroll
                    for (int dx = 0; dx < 3; ++dx)
                        wq[o][dx] = wb[o * 3456 + (dz * 3 + dy) * 3 + dx];
#pragma unroll
                for (int o = 0; o < 3; ++o)
#pragma unroll
                    for (int j = 0; j < 4; ++j)
#pragma unroll
                        for (int dx = 0; dx < 3; ++dx)
                            acc[o][j] = fmaf(wq[o][dx], v[j + dx], acc[o][j]);
            }
        }
    }
#undef STAGE

    const int oz = d0 + tz, oy = h0 + ty, ox = w0 + 4 * xo;
    const size_t base = ((size_t)(split * 2 + n)) * 3 * 65536;
    const int p = oz * 4096 + oy * 64 + ox;
#pragma unroll
    for (int o = 0; o < 3; ++o)
        *(float4*)(part + base + (size_t)o * 65536 + p) =
            make_float4(acc[o][0], acc[o][1], acc[o][2], acc[o][3]);
}

// ---------------- kernel F2: kcomb x4 only (128 blocks) ----------------
__global__ __launch_bounds__(256) void kpost(const float* __restrict__ part,
                                             float* __restrict__ vg) {
    int gid = blockIdx.x * 256 + threadIdx.x;      // 0..32767
    int n = gid >> 14, p4 = (gid & 16383) * 4;
    float4 s0 = make_float4(0.f, 0.f, 0.f, 0.f);
    float4 s1 = s0, s2 = s0;
    for (int s = 0; s < 16; ++s) {
        const float* bp = part + ((size_t)(s * 2 + n)) * 3 * 65536 + p4;
        float4 a = *(const float4*)(bp);
        float4 b4 = *(const float4*)(bp + 65536);
        float4 c4 = *(const float4*)(bp + 131072);
        s0.x += a.x; s0.y += a.y; s0.z += a.z; s0.w += a.w;
        s1.x += b4.x; s1.y += b4.y; s1.z += b4.z; s1.w += b4.w;
        s2.x += c4.x; s2.y += c4.y; s2.z += c4.z; s2.w += c4.w;
    }
    int w = p4 & 63, h = (p4 >> 6) & 63, d = p4 >> 12;
    size_t vb = (size_t)n * 3 * 65536;
    *(float4*)(vg + vb + p4) = make_float4(
        ((float)(w + 0) + s0.x) * (1.0f / 64.0f), ((float)(w + 1) + s0.y) * (1.0f / 64.0f),
        ((float)(w + 2) + s0.z) * (1.0f / 64.0f), ((float)(w + 3) + s0.w) * (1.0f / 64.0f));
    *(float4*)(vg + vb + 65536 + p4) = make_float4(
        ((float)h + s1.x) * (1.0f / 64.0f), ((float)h + s1.y) * (1.0f / 64.0f),
        ((float)h + s1.z) * (1.0f / 64.0f), ((float)h + s1.w) * (1.0f / 64.0f));
    *(float4*)(vg + vb + 131072 + p4) = make_float4(
        ((float)d + s2.x) * (1.0f / 16.0f), ((float)d + s2.y) * (1.0f / 16.0f),
        ((float)d + s2.z) * (1.0f / 16.0f), ((float)d + s2.w) * (1.0f / 16.0f));
}

// ---------------- kernel G: grid_sample v4 — precomputed weights, 2-point ILP ----------------
// Phase 1: threads 0..63 compute 64 points' corner weights+indices into LDS (broadcasts).
// Main loop: 2 points per iteration -> 16 independent gathers in flight per thread
// (double the MLP of v2), two accumulator pairs. Single [128][65] transpose buffer.
__global__ __launch_bounds__(256) void ksample(const float* __restrict__ yt,
                                               const float* __restrict__ vg,
                                               float* __restrict__ out) {
    const int b = blockIdx.x;        // 2048
    const int n = b >> 10;
    const int p0 = (b & 1023) << 6;  // 64 points per block
    const int tid = threadIdx.x;
    const int lane = tid & 63;
    const int wv = tid >> 6;         // 0..3

    __shared__ float lds[128 * 65];  // [c][pt], pad 65
    __shared__ float s_w[8][64];
    __shared__ int   s_idx[8][64];

    const float* ytn = yt + (size_t)n * 8192 * 128;
    const size_t vb = (size_t)n * 3 * 65536;

    // phase 1: one thread per point
    if (tid < 64) {
        const int p = p0 + tid;
        float gx = vg[vb + p], gy = vg[vb + 65536 + p], gz = vg[vb + 131072 + p];
        float ix = ((gx + 1.f) * 32.f - 1.f) * 0.5f;
        float iy = ((gy + 1.f) * 32.f - 1.f) * 0.5f;
        float iz = ((gz + 1.f) * 8.f - 1.f) * 0.5f;
        int x0 = (int)floorf(ix), y0 = (int)floorf(iy), z0 = (int)floorf(iz);
        float fx = ix - (float)x0, fy = iy - (float)y0, fz = iz - (float)z0;
        float wx[2] = {1.f - fx, fx}, wy[2] = {1.f - fy, fy}, wz[2] = {1.f - fz, fz};
#pragma unroll
        for (int k = 0; k < 8; ++k) {
            int dz = k >> 2, dy = (k >> 1) & 1, dx = k & 1;
            int zc = z0 + dz, yc = y0 + dy, xc = x0 + dx;
            bool valid = ((unsigned)zc < 8u) && ((unsigned)yc < 32u) && ((unsigned)xc < 32u);
            int zcl = min(max(zc, 0), 7), ycl = min(max(yc, 0), 31), xcl = min(max(xc, 0), 31);
            s_idx[k][tid] = (zcl * 32 + ycl) * 32 + xcl;
            float wgt = wz[dz] * wy[dy] * wx[dx];
            s_w[k][tid] = valid ? wgt : 0.f;
        }
    }
    __syncthreads();

    for (int q = 0; q < 16; q += 2) {
        const int pt0 = wv * 16 + q;     // wave-uniform
        const int pt1 = pt0 + 1;
        float ax0 = 0.f, ay0 = 0.f, ax1 = 0.f, ay1 = 0.f;
#pragma unroll
        for (int k = 0; k < 8; ++k) {
            const float wk0 = s_w[k][pt0];
            const int ik0 = s_idx[k][pt0];
            const float wk1 = s_w[k][pt1];
            const int ik1 = s_idx[k][pt1];
            const float2 v0 = *(const float2*)(ytn + (size_t)ik0 * 128 + 2 * lane);
            const float2 v1 = *(const float2*)(ytn + (size_t)ik1 * 128 + 2 * lane);
            ax0 = fmaf(wk0, v0.x, ax0);
            ay0 = fmaf(wk0, v0.y, ay0);
            ax1 = fmaf(wk1, v1.x, ax1);
            ay1 = fmaf(wk1, v1.y, ay1);
        }
        lds[(2 * lane) * 65 + pt0] = ax0;
        lds[(2 * lane + 1) * 65 + pt0] = ay0;
        lds[(2 * lane) * 65 + pt1] = ax1;
        lds[(2 * lane + 1) * 65 + pt1] = ay1;
    }
    __syncthreads();
    // coalesced store: 128 channel-rows of 64 points
    const int pw = tid & 63, cw = tid >> 6;
    float* ob = out + (size_t)n * 128 * 65536 + p0 + pw;
#pragma unroll
    for (int k = 0; k < 32; ++k) {
        int c = k * 4 + cw;
        ob[(size_t)c * 65536] = lds[c * 65 + pw];
    }
}

extern "C" void kernel_launch(void* const* d_in, const int* in_sizes, int n_in,
                              void* d_out, int out_size, void* d_ws, size_t ws_size,
                              hipStream_t stream) {
    const float* x     = (const float*)d_in[0];
    const float* y     = (const float*)d_in[1];
    const float* wdh   = (const float*)d_in[2];
    const float* wdl   = (const float*)d_in[3];
    const float* wflow = (const float*)d_in[4];
    const float* watt  = (const float*)d_in[5];
    const float* wconv = (const float*)d_in[6];
    float* out = (float*)d_out;

    float* ws     = (float*)d_ws;
    float* meanx  = ws + MEANX_OFF;   // 128
    float* weff   = ws + WEFF_OFF;    // 10368
    float* hf     = ws + HF_OFF;      // 1048576
    float* hfup   = ws + HFUP_OFF;    // 8388608
    float* vg     = ws + VG_OFF;      // 393216
    float* zpage  = ws + ZPAGE_OFF;   // 64
    float* yt     = ws + YT_OFF;      // 2097152

    // partials live in d_out (16*2*3*65536 = 6.29M floats <= 16.77M);
    // low splits written by kmid, high splits by kflowp; kpost reads after kflowp.
    float* part = out;

    kearly<<<896, 256, 0, stream>>>(x, y, wdh, meanx, hf, yt, zpage);     // kmean ∪ kconvh ∪ ktrans
    kprep<<<2, 256, 0, stream>>>(wdl, watt, wconv, wflow, meanx, weff);   // SE + weight fold
    kmid<<<17408, 256, 0, stream>>>(x, ws, weff, hf, hfup, part);         // kflowp_low ∪ kups
    kflowp<<<1024, 256, 0, stream>>>(ws, wflow, part);                    // kflowp_high
    kpost<<<128, 256, 0, stream>>>(part, vg);                             // kcomb(x4)
    ksample<<<2048, 256, 0, stream>>>(yt, vg, out);
}

// Round 28
// 158.667 us; speedup vs baseline: 1.0816x; 1.0816x over previous
//
#include <hip/hip_runtime.h>
#include <math.h>

// x [2,64,16,64,64], y [2,128,8,32,32]
// w_down_h [64,128], w_down_l [64,64], w_flow [3,128,3,3,3],
// w_att_atten [64,64], w_att_conv [64,64]
// out = grid_sample(y, vgrid) -> [2,128,16,64,64] fp32

// ws layout (float offsets) — total 17842240 floats = 71.4 MB (< 72.9 MB proven)
#define MEANX_OFF  0
#define WEFF_OFF   128        // [2][64][3][27] = 10368
#define HF_OFF     16384      // 1048576
#define HFUP_OFF   1064960    // 8388608
#define ZPAGE_OFF  9453568    // 64
#define YT_OFF     9453632    // 2097152
#define PART_OFF   11550784   // 6291456 (partials now in ws — ksample writes d_out freely)

// ---------------- kernel A: kmean (0..127) + kconvh (128..383) + ktrans (384..895) ----------------
__global__ __launch_bounds__(256) void kearly(const float* __restrict__ x,
                                              const float* __restrict__ y,
                                              const float* __restrict__ wdh,
                                              float* __restrict__ meanx,
                                              float* __restrict__ hf,
                                              float* __restrict__ yt,
                                              float* __restrict__ zpage) {
    const int blk = blockIdx.x;
    if (blk < 128) {
        // ---- kmean ----
        if (blk == 0 && threadIdx.x < 64) zpage[threadIdx.x] = 0.f;
        int ch = blk;  // 0..127  (n*64+c)
        const float4* base = (const float4*)(x + (size_t)ch * 65536);
        float s = 0.f;
        for (int j = threadIdx.x; j < 16384; j += 256) {
            float4 v = base[j];
            s += v.x + v.y + v.z + v.w;
        }
        __shared__ float red[256];
        red[threadIdx.x] = s;
        __syncthreads();
        for (int off = 128; off > 0; off >>= 1) {
            if (threadIdx.x < off) red[threadIdx.x] += red[threadIdx.x + off];
            __syncthreads();
        }
        if (threadIdx.x == 0) meanx[ch] = red[0] * (1.0f / 65536.0f);
    } else if (blk < 384) {
        // ---- kconvh ----
        const int b = blk - 128;    // 0..255
        const int n = b >> 7;
        const int r = b & 127;
        const int os = r & 3;       // 16 outputs each
        const int tile = r >> 2;    // 0..31, 256 points
        const int p = tile * 256 + threadIdx.x;
        const float* yb = y + (size_t)n * 128 * 8192 + p;

        float acc[16];
#pragma unroll
        for (int o = 0; o < 16; ++o) acc[o] = 0.f;

        for (int i = 0; i < 128; i += 4) {
            const float yi0 = yb[(size_t)(i + 0) * 8192];
            const float yi1 = yb[(size_t)(i + 1) * 8192];
            const float yi2 = yb[(size_t)(i + 2) * 8192];
            const float yi3 = yb[(size_t)(i + 3) * 8192];
#pragma unroll
            for (int o = 0; o < 16; ++o) {
                float a = acc[o];
                a = fmaf(wdh[(os * 16 + o) * 128 + i + 0], yi0, a);
                a = fmaf(wdh[(os * 16 + o) * 128 + i + 1], yi1, a);
                a = fmaf(wdh[(os * 16 + o) * 128 + i + 2], yi2, a);
                a = fmaf(wdh[(os * 16 + o) * 128 + i + 3], yi3, a);
                acc[o] = a;
            }
        }
        float* ob = hf + (size_t)(n * 64 + os * 16) * 8192 + p;
#pragma unroll
        for (int o = 0; o < 16; ++o)
            ob[(size_t)o * 8192] = acc[o];
    } else {
        // ---- ktrans: y -> channel-last yt [n][8192][128] ----
        int b = blk - 384;        // 0..511
        int n = b >> 8;
        int rem = b & 255;        // 2 c-tiles * 128 s-tiles
        int ct = rem >> 7, st = rem & 127;
        int c0 = ct * 64, s0 = st * 64;
        __shared__ float t[64][65];
        int tx = threadIdx.x & 63, ty = threadIdx.x >> 6;  // 4 rows/pass
#pragma unroll
        for (int k = 0; k < 16; ++k)
            t[ty + 4 * k][tx] = y[((size_t)(n * 128 + c0 + ty + 4 * k)) * 8192 + s0 + tx];
        __syncthreads();
#pragma unroll
        for (int k = 0; k < 16; ++k)
            yt[((size_t)(n * 8192 + s0 + ty + 4 * k)) * 128 + c0 + tx] = t[tx][ty + 4 * k];
    }
}

// ---------------- kernel B: SE weights + fold low-branch conv weights -> weff ----------------
__global__ __launch_bounds__(256) void kprep(const float* __restrict__ wdl,
                                             const float* __restrict__ watt,
                                             const float* __restrict__ wconv,
                                             const float* __restrict__ wflow,
                                             const float* __restrict__ meanx,
                                             float* __restrict__ weff) {
    const int n = blockIdx.x;   // 2
    const int tid = threadIdx.x;
    __shared__ float s_wdl[4096];   // wdl[j][i]; later reused as s_comb[i][c]
    __shared__ float s_wcT[4096];   // wconv transposed: [j][o]
    __shared__ float s_flow[5184];  // wflow low half: [o*1728 + c*27 + tap]
    __shared__ float pooled[64], sc[64];
    for (int k = tid; k < 4096; k += 256) {
        s_wdl[k] = wdl[k];
        int o = k >> 6, j = k & 63;
        s_wcT[j * 64 + o] = wconv[k];
    }
    for (int k = tid; k < 5184; k += 256) {
        int o = k / 1728, r = k - o * 1728;
        s_flow[k] = wflow[o * 3456 + 1728 + r];
    }
    __syncthreads();
    if (tid < 64) {
        float p = 0.f;
        for (int i = 0; i < 64; ++i) p += s_wdl[tid * 64 + i] * meanx[n * 64 + i];
        pooled[tid] = p;
    }
    __syncthreads();
    if (tid < 64) {
        float a = 0.f;
        for (int i = 0; i < 64; ++i) a += watt[tid * 64 + i] * pooled[i];
        sc[tid] = 1.f + 1.f / (1.f + expf(-a));
    }
    __syncthreads();
    float wc[16];
#pragma unroll
    for (int k = 0; k < 16; ++k) {
        const int idx = tid + 256 * k;
        const int o = idx & 63, i = idx >> 6;
        float acc = 0.f;
#pragma unroll 8
        for (int j = 0; j < 64; ++j)
            acc += s_wcT[j * 64 + o] * (sc[j] * s_wdl[j * 64 + i]);
        wc[k] = acc;
    }
    __syncthreads();
#pragma unroll
    for (int k = 0; k < 16; ++k) {
        const int idx = tid + 256 * k;
        const int o = idx & 63, i = idx >> 6;
        s_wdl[i * 64 + o] = wc[k];   // s_comb[i*64 + c] = W_comb[c][i]
    }
    __syncthreads();
    for (int e = tid; e < 5184; e += 256) {
        const int i = e / 81, r = e - i * 81;
        const int o = r / 27, tap = r - o * 27;
        float acc = 0.f;
#pragma unroll 8
        for (int c = 0; c < 64; ++c)
            acc += s_flow[o * 1728 + c * 27 + tap] * s_wdl[i * 64 + c];
        weff[n * 5184 + e] = acc;
    }
}

// ---------------- kernel C: fused kflowp_low (blocks 0..1023) + kups (1024..17407) ----------------
__global__ __launch_bounds__(256) void kmid(const float* __restrict__ x,
                                            const float* __restrict__ ws,
                                            const float* __restrict__ weff,
                                            const float* __restrict__ hf,
                                            float* __restrict__ hfup,
                                            float* __restrict__ part) {
    const int blk = blockIdx.x;
    if (blk < 1024) {
        // ---- kflowp_low: splits 8..15, source x, weights weff ----
        const int tid = threadIdx.x;
        const int sp = blk & 7;              // 0..7 -> x channels sp*8..sp*8+7
        const int tile = blk >> 3;           // 0..127
        const int n = tile >> 6;
        const int t = tile & 63;
        const int td = t >> 4, th = (t >> 2) & 3, tw = t & 3;
        const int d0 = td * 4, h0 = th * 16, w0 = tw * 16;
        const int xo = tid & 3, ty = (tid >> 2) & 15, tz = tid >> 6;
        const int wv = tid >> 6;

        __shared__ float lds[3][2048];

        const float* gb = x + (size_t)(n * 64 + sp * 8) * 65536;
        const float* zp = ws + ZPAGE_OFF;

        const float* addrk[8];
        int vmask = 0;
#pragma unroll
        for (int k = 0; k < 8; ++k) {
            const int e = tid + 256 * k;
            const int r = e / 18;
            const int lx = e - r * 18;
            const int z = r / 18;
            const int ly = r - z * 18;
            const int gz = d0 - 1 + z, gy = h0 - 1 + ly, gx = w0 - 1 + lx;
            const bool ok = (e < 1944) && ((unsigned)gz < 16u) && ((unsigned)gy < 64u) &&
                            ((unsigned)gx < 64u);
            addrk[k] = ok ? (gb + (gz * 4096 + gy * 64 + gx)) : zp;
            vmask |= (ok ? 1 : 0) << k;
        }

#define STAGEL(BUFI)                                                                  \
    {                                                                                 \
        _Pragma("unroll")                                                             \
        for (int k = 0; k < 8; ++k) {                                                 \
            __builtin_amdgcn_global_load_lds(                                         \
                (const __attribute__((address_space(1))) unsigned int*)(addrk[k]),    \
                (__attribute__((address_space(3))) unsigned int*)                     \
                    (&lds[BUFI][wv * 64 + 256 * k]),                                  \
                4, 0, 0);                                                             \
            addrk[k] += ((vmask >> k) & 1) ? 65536 : 0;                               \
        }                                                                             \
    }

        float acc[3][4];
#pragma unroll
        for (int o = 0; o < 3; ++o)
#pragma unroll
            for (int j = 0; j < 4; ++j) acc[o][j] = 0.f;

        STAGEL(0);

        for (int ci = 0; ci < 8; ++ci) {
            const int cur = ci % 3;
            if (ci < 7) {
                STAGEL((ci + 1) % 3);
                asm volatile("s_waitcnt vmcnt(8)" ::: "memory");
            } else {
                asm volatile("s_waitcnt vmcnt(0)" ::: "memory");
            }
            __builtin_amdgcn_s_barrier();
            __builtin_amdgcn_sched_barrier(0);

            const int cidx = __builtin_amdgcn_readfirstlane(sp * 8 + ci);
            const float* wbase = weff + (size_t)n * 5184 + (size_t)cidx * 81;
            const float* buf = lds[cur];
#pragma unroll
            for (int dz = 0; dz < 3; ++dz) {
#pragma unroll
                for (int dy = 0; dy < 3; ++dy) {
                    const float* rp = &buf[((tz + dz) * 18 + ty + dy) * 18 + 4 * xo];
                    const float2 a0 = *(const float2*)(rp);
                    const float2 a1 = *(const float2*)(rp + 2);
                    const float2 a2 = *(const float2*)(rp + 4);
                    const float v[6] = {a0.x, a0.y, a1.x, a1.y, a2.x, a2.y};
                    float wq[3][3];
#pragma unroll
                    for (int o = 0; o < 3; ++o)
#pragma unroll
                        for (int dx = 0; dx < 3; ++dx)
                            wq[o][dx] = wbase[o * 27 + (dz * 3 + dy) * 3 + dx];
#pragma unroll
                    for (int o = 0; o < 3; ++o)
#pragma unroll
                        for (int j = 0; j < 4; ++j)
#pragma unroll
                            for (int dx = 0; dx < 3; ++dx)
                                acc[o][j] = fmaf(wq[o][dx], v[j + dx], acc[o][j]);
                }
            }
        }
#undef STAGEL

        const int oz = d0 + tz, oy = h0 + ty, ox = w0 + 4 * xo;
        const size_t base = ((size_t)((sp + 8) * 2 + n)) * 3 * 65536;
        const int p = oz * 4096 + oy * 64 + ox;
#pragma unroll
        for (int o = 0; o < 3; ++o)
            *(float4*)(part + base + (size_t)o * 65536 + p) =
                make_float4(acc[o][0], acc[o][1], acc[o][2], acc[o][3]);
    } else {
        // ---- kups (2 w-outputs/thread) ----
        int id2 = (blk - 1024) * 256 + threadIdx.x;  // 4194304 total
        int wp = id2 & 31, h = (id2 >> 5) & 63, d = (id2 >> 11) & 15;
        int c = (id2 >> 15) & 63, n = id2 >> 21;
        const float SD = 7.0f / 15.0f, SH = 31.0f / 63.0f;
        float pd = (float)d * SD, ph = (float)h * SH;
        int z0 = (int)pd; if (z0 > 7) z0 = 7;
        int z1 = min(z0 + 1, 7); float fz = pd - (float)z0;
        int y0 = (int)ph; if (y0 > 31) y0 = 31;
        int y1 = min(y0 + 1, 31); float fy = ph - (float)y0;

        const int w0i = 2 * wp, w1i = 2 * wp + 1;
        float pw0 = (float)w0i * SH, pw1 = (float)w1i * SH;
        int xa = (int)pw0; if (xa > 31) xa = 31;
        float fx0 = pw0 - (float)xa;
        int xb2 = (int)pw1; if (xb2 > 31) xb2 = 31;
        float fx1 = pw1 - (float)xb2;

        const float* b = hf + (size_t)(n * 64 + c) * 8192;
        const int r00 = (z0 * 32 + y0) * 32, r01 = (z0 * 32 + y1) * 32;
        const int r10 = (z1 * 32 + y0) * 32, r11 = (z1 * 32 + y1) * 32;
        const float wzy00 = (1.f - fz) * (1.f - fy), wzy01 = (1.f - fz) * fy;
        const float wzy10 = fz * (1.f - fy), wzy11 = fz * fy;

        float colv[3];
#pragma unroll
        for (int j = 0; j < 3; ++j) {
            int xc = min(xa + j, 31);
            colv[j] = wzy00 * b[r00 + xc] + wzy01 * b[r01 + xc] +
                      wzy10 * b[r10 + xc] + wzy11 * b[r11 + xc];
        }
        float o0 = colv[0] + (colv[1] - colv[0]) * fx0;
        int i1 = xb2 - xa;  // 0 or 1
        float lo = (i1 == 0) ? colv[0] : colv[1];
        float hi = (i1 == 0) ? colv[1] : colv[2];
        float o1 = lo + (hi - lo) * fx1;

        *(float2*)(hfup + ((size_t)id2 * 2)) = make_float2(o0, o1);
    }
}

// ---------------- kernel F: kflowp_high — splits 0..7 (hfup, wflow), int-offset form ----------------
__global__ __launch_bounds__(256) void kflowp(const float* __restrict__ ws,
                                              const float* __restrict__ wflow,
                                              float* __restrict__ part) {
    const int tid = threadIdx.x;
    const int b = blockIdx.x;            // 1024
    const int split = b & 7;             // 8 channels each (hfup channels)
    const int tile = b >> 3;             // 0..127
    const int n = tile >> 6;
    const int t = tile & 63;
    const int td = t >> 4, th = (t >> 2) & 3, tw = t & 3;
    const int d0 = td * 4, h0 = th * 16, w0 = tw * 16;
    const int xo = tid & 3, ty = (tid >> 2) & 15, tz = tid >> 6;
    const int wv = tid >> 6;

    __shared__ float lds[3][2048];

    const int srcb = HFUP_OFF + (n * 64 + split * 8) * 65536;

    int woff[8];
#pragma unroll
    for (int k = 0; k < 8; ++k) {
        const int e = tid + 256 * k;
        const int r = e / 18;
        const int lx = e - r * 18;
        const int z = r / 18;
        const int ly = r - z * 18;
        const int gz = d0 - 1 + z, gy = h0 - 1 + ly, gx = w0 - 1 + lx;
        const bool ok = (e < 1944) && ((unsigned)gz < 16u) && ((unsigned)gy < 64u) &&
                        ((unsigned)gx < 64u);
        woff[k] = ok ? (srcb + gz * 4096 + gy * 64 + gx) : ZPAGE_OFF;
    }

#define STAGE(BUFI, CI)                                                               \
    {                                                                                 \
        _Pragma("unroll")                                                             \
        for (int k = 0; k < 8; ++k) {                                                 \
            const int off = woff[k] + ((woff[k] < ZPAGE_OFF) ? (CI) * 65536 : 0);     \
            __builtin_amdgcn_global_load_lds(                                         \
                (const __attribute__((address_space(1))) unsigned int*)(ws + off),    \
                (__attribute__((address_space(3))) unsigned int*)                     \
                    (&lds[BUFI][wv * 64 + 256 * k]),                                  \
                4, 0, 0);                                                             \
        }                                                                             \
    }

    float acc[3][4];
#pragma unroll
    for (int o = 0; o < 3; ++o)
#pragma unroll
        for (int j = 0; j < 4; ++j) acc[o][j] = 0.f;

    STAGE(0, 0);

    for (int ci = 0; ci < 8; ++ci) {
        const int cur = ci % 3;
        if (ci < 7) {
            STAGE((ci + 1) % 3, ci + 1);
            asm volatile("s_waitcnt vmcnt(8)" ::: "memory");
        } else {
            asm volatile("s_waitcnt vmcnt(0)" ::: "memory");
        }
        __builtin_amdgcn_s_barrier();
        __builtin_amdgcn_sched_barrier(0);

        const int cgs = __builtin_amdgcn_readfirstlane(split * 8 + ci);
        const float* wb = wflow + (size_t)cgs * 27;   // SGPR base -> s_loads
        const float* buf = lds[cur];
#pragma unroll
        for (int dz = 0; dz < 3; ++dz) {
#pragma unroll
            for (int dy = 0; dy < 3; ++dy) {
                const float* rp = &buf[((tz + dz) * 18 + ty + dy) * 18 + 4 * xo];
                const float2 a0 = *(const float2*)(rp);
                const float2 a1 = *(const float2*)(rp + 2);
                const float2 a2 = *(const float2*)(rp + 4);
                const float v[6] = {a0.x, a0.y, a1.x, a1.y, a2.x, a2.y};
                float wq[3][3];
#pragma unroll
                for (int o = 0; o < 3; ++o)
#pragma unroll
                    for (int dx = 0; dx < 3; ++dx)
                        wq[o][dx] = wb[o * 3456 + (dz * 3 + dy) * 3 + dx];
#pragma unroll
                for (int o = 0; o < 3; ++o)
#pragma unroll
                    for (int j = 0; j < 4; ++j)
#pragma unroll
                        for (int dx = 0; dx < 3; ++dx)
                            acc[o][j] = fmaf(wq[o][dx], v[j + dx], acc[o][j]);
            }
        }
    }
#undef STAGE

    const int oz = d0 + tz, oy = h0 + ty, ox = w0 + 4 * xo;
    const size_t base = ((size_t)(split * 2 + n)) * 3 * 65536;
    const int p = oz * 4096 + oy * 64 + ox;
#pragma unroll
    for (int o = 0; o < 3; ++o)
        *(float4*)(part + base + (size_t)o * 65536 + p) =
            make_float4(acc[o][0], acc[o][1], acc[o][2], acc[o][3]);
}

// ---------------- kernel G: grid_sample v5 — fused partial-combine + r25-v2 gather loop ----------------
// Phase 1a: threads 0..191 reduce the 16 partials for (o, pt) pairs (coalesced rows).
// Phase 1b: threads 0..63 compute corner weights+indices from the sums.
// Main: r25's proven single-pass loop — broadcast weights, coalesced float2 gathers,
// [128][65] transpose, coalesced store. kpost/vg eliminated.
__global__ __launch_bounds__(256) void ksample(const float* __restrict__ yt,
                                               const float* __restrict__ part,
                                               float* __restrict__ out) {
    const int b = blockIdx.x;        // 2048
    const int n = b >> 10;
    const int p0 = (b & 1023) << 6;  // 64 points per block
    const int tid = threadIdx.x;
    const int lane = tid & 63;
    const int wv = tid >> 6;         // 0..3

    __shared__ float lds[128 * 65];  // [c][pt], pad 65
    __shared__ float s_sum[3][64];
    __shared__ float s_w[8][64];
    __shared__ int   s_idx[8][64];

    const float* ytn = yt + (size_t)n * 8192 * 128;

    // phase 1a: combine partials (o = tid>>6, pt = tid&63); lanes coalesced over pt
    if (tid < 192) {
        const int o = tid >> 6, pt = tid & 63;
        const int p = p0 + pt;
        float s = 0.f;
#pragma unroll
        for (int sp = 0; sp < 16; ++sp)
            s += part[((size_t)(sp * 2 + n) * 3 + o) * 65536 + p];
        s_sum[o][pt] = s;
    }
    __syncthreads();

    // phase 1b: per-point corner weights + indices
    if (tid < 64) {
        const int p = p0 + tid;
        const int w = p & 63, h = (p >> 6) & 63, d = p >> 12;
        float gx = ((float)w + s_sum[0][tid]) * (1.0f / 64.0f);
        float gy = ((float)h + s_sum[1][tid]) * (1.0f / 64.0f);
        float gz = ((float)d + s_sum[2][tid]) * (1.0f / 16.0f);
        float ix = ((gx + 1.f) * 32.f - 1.f) * 0.5f;
        float iy = ((gy + 1.f) * 32.f - 1.f) * 0.5f;
        float iz = ((gz + 1.f) * 8.f - 1.f) * 0.5f;
        int x0 = (int)floorf(ix), y0 = (int)floorf(iy), z0 = (int)floorf(iz);
        float fx = ix - (float)x0, fy = iy - (float)y0, fz = iz - (float)z0;
        float wx[2] = {1.f - fx, fx}, wy[2] = {1.f - fy, fy}, wz[2] = {1.f - fz, fz};
#pragma unroll
        for (int k = 0; k < 8; ++k) {
            int dz = k >> 2, dy = (k >> 1) & 1, dx = k & 1;
            int zc = z0 + dz, yc = y0 + dy, xc = x0 + dx;
            bool valid = ((unsigned)zc < 8u) && ((unsigned)yc < 32u) && ((unsigned)xc < 32u);
            int zcl = min(max(zc, 0), 7), ycl = min(max(yc, 0), 31), xcl = min(max(xc, 0), 31);
            s_idx[k][tid] = (zcl * 32 + ycl) * 32 + xcl;
            float wgt = wz[dz] * wy[dy] * wx[dx];
            s_w[k][tid] = valid ? wgt : 0.f;
        }
    }
    __syncthreads();

    for (int q = 0; q < 16; ++q) {
        const int pt = wv * 16 + q;  // 0..63, wave-uniform
        float ax = 0.f, ay = 0.f;
#pragma unroll
        for (int k = 0; k < 8; ++k) {
            const float wk = s_w[k][pt];    // broadcast
            const int ik = s_idx[k][pt];    // broadcast
            const float2 v = *(const float2*)(ytn + (size_t)ik * 128 + 2 * lane);
            ax = fmaf(wk, v.x, ax);
            ay = fmaf(wk, v.y, ay);
        }
        lds[(2 * lane) * 65 + pt] = ax;
        lds[(2 * lane + 1) * 65 + pt] = ay;
    }
    __syncthreads();
    // coalesced store: 128 channel-rows of 64 points
    const int pw = tid & 63, cw = tid >> 6;
    float* ob = out + (size_t)n * 128 * 65536 + p0 + pw;
#pragma unroll
    for (int k = 0; k < 32; ++k) {
        int c = k * 4 + cw;
        ob[(size_t)c * 65536] = lds[c * 65 + pw];
    }
}

extern "C" void kernel_launch(void* const* d_in, const int* in_sizes, int n_in,
                              void* d_out, int out_size, void* d_ws, size_t ws_size,
                              hipStream_t stream) {
    const float* x     = (const float*)d_in[0];
    const float* y     = (const float*)d_in[1];
    const float* wdh   = (const float*)d_in[2];
    const float* wdl   = (const float*)d_in[3];
    const float* wflow = (const float*)d_in[4];
    const float* watt  = (const float*)d_in[5];
    const float* wconv = (const float*)d_in[6];
    float* out = (float*)d_out;

    float* ws     = (float*)d_ws;
    float* meanx  = ws + MEANX_OFF;   // 128
    float* weff   = ws + WEFF_OFF;    // 10368
    float* hf     = ws + HF_OFF;      // 1048576
    float* hfup   = ws + HFUP_OFF;    // 8388608
    float* zpage  = ws + ZPAGE_OFF;   // 64
    float* yt     = ws + YT_OFF;      // 2097152
    float* part   = ws + PART_OFF;    // 6291456 (in ws now — no d_out aliasing)

    kearly<<<896, 256, 0, stream>>>(x, y, wdh, meanx, hf, yt, zpage);     // kmean ∪ kconvh ∪ ktrans
    kprep<<<2, 256, 0, stream>>>(wdl, watt, wconv, wflow, meanx, weff);   // SE + weight fold
    kmid<<<17408, 256, 0, stream>>>(x, ws, weff, hf, hfup, part);         // kflowp_low ∪ kups
    kflowp<<<1024, 256, 0, stream>>>(ws, wflow, part);                    // kflowp_high
    ksample<<<2048, 256, 0, stream>>>(yt, part, out);                     // combine ∪ grid_sample
}